// Round 2
// baseline (657.420 us; speedup 1.0000x reference)
//
#include <hip/hip_runtime.h>
#include <math.h>

#define NB 16   // batches
#define NP 900  // predictions (solver columns)
#define NC 91   // classes
#define NT 100  // targets (solver rows)
#define SLOTS 15  // ceil(NP/64) columns owned per lane

// ---------------------------------------------------------------------------
// Kernel A: per-(b,n) softmax stats (max, sum). One 64-lane wave per row.
// ---------------------------------------------------------------------------
__global__ __launch_bounds__(256) void softmax_stats_kernel(
    const float* __restrict__ cls_pred,   // [B*N, K]
    float2* __restrict__ stats)           // [B*N] (max, sum)
{
    const int wave = (blockIdx.x * 256 + threadIdx.x) >> 6;
    const int lane = threadIdx.x & 63;
    if (wave >= NB * NP) return;
    const float* crow = cls_pred + (size_t)wave * NC;

    const float x0 = crow[lane];                                  // lane < 91 always
    const float x1 = (lane + 64 < NC) ? crow[lane + 64] : -INFINITY;
    float mx = fmaxf(x0, x1);
    #pragma unroll
    for (int off = 32; off >= 1; off >>= 1)
        mx = fmaxf(mx, __shfl_xor(mx, off, 64));

    float s = expf(x0 - mx);
    if (lane + 64 < NC) s += expf(x1 - mx);
    #pragma unroll
    for (int off = 32; off >= 1; off >>= 1)
        s += __shfl_xor(s, off, 64);

    if (lane == 0) stats[wave] = make_float2(mx, s);
}

// ---------------------------------------------------------------------------
// Kernel B: one thread per cost entry. Ct[b][m][n] = 5*l1 - 2*iou - prob.
// ---------------------------------------------------------------------------
__global__ __launch_bounds__(256) void cost_entry_kernel(
    const float* __restrict__ cls_pred,   // [B,N,K]
    const float* __restrict__ bb_pred,    // [B,N,4]
    const int*   __restrict__ cls_gt,     // [B,M]
    const float* __restrict__ bb_gt,      // [B,M,4]
    const float2* __restrict__ stats,     // [B*N]
    float* __restrict__ Ct)               // [B,M,N]
{
    const int idx = blockIdx.x * 256 + threadIdx.x;
    if (idx >= NB * NT * NP) return;
    const int n  = idx % NP;
    const int bm = idx / NP;
    const int m  = bm % NT;
    const int b  = bm / NT;

    const float4 bp = *reinterpret_cast<const float4*>(bb_pred + ((size_t)b*NP + n)*4);
    const float4 gt = *reinterpret_cast<const float4*>(bb_gt  + ((size_t)b*NT + m)*4);

    const float l1 = fabsf(bp.x - gt.x) + fabsf(bp.y - gt.y) +
                     fabsf(bp.z - gt.z) + fabsf(bp.w - gt.w);

    const float parea = (bp.z - bp.x) * (bp.w - bp.y);
    const float garea = (gt.z - gt.x) * (gt.w - gt.y);
    const float xm = fmaxf(bp.x, gt.x);
    const float ym = fmaxf(bp.y, gt.y);
    const float xM = fminf(bp.z, gt.z);
    const float yM = fminf(bp.w, gt.w);
    const float inter = fmaxf(xM - xm, 0.f) * fmaxf(yM - ym, 0.f);
    const float iou = inter / (parea + garea - inter + 1e-6f);

    const int c = cls_gt[b*NT + m];
    const float2 st = stats[b*NP + n];
    const float pc = expf(cls_pred[((size_t)(b*NP + n))*NC + c] - st.x) / st.y;

    Ct[idx] = 5.0f*l1 - 2.0f*iou - pc;
}

// ---------------------------------------------------------------------------
// Fallback fused cost kernel (used only if ws_size is too small for stats).
// ---------------------------------------------------------------------------
__global__ __launch_bounds__(256) void cost_fused_kernel(
    const float* __restrict__ cls_pred, const float* __restrict__ bb_pred,
    const int* __restrict__ cls_gt, const float* __restrict__ bb_gt,
    float* __restrict__ Ct)
{
    const int b = blockIdx.y;
    const int n = blockIdx.x * 256 + threadIdx.x;
    __shared__ float gx0[NT], gy0[NT], gx1[NT], gy1[NT], garea[NT];
    __shared__ int   gcls[NT];
    for (int m = threadIdx.x; m < NT; m += 256) {
        const float x0 = bb_gt[((size_t)b*NT + m)*4 + 0];
        const float y0 = bb_gt[((size_t)b*NT + m)*4 + 1];
        const float x1 = bb_gt[((size_t)b*NT + m)*4 + 2];
        const float y1 = bb_gt[((size_t)b*NT + m)*4 + 3];
        gx0[m] = x0; gy0[m] = y0; gx1[m] = x1; gy1[m] = y1;
        garea[m] = (x1 - x0) * (y1 - y0);
        gcls[m]  = cls_gt[b*NT + m];
    }
    __syncthreads();
    if (n >= NP) return;
    const float4 bp = *reinterpret_cast<const float4*>(bb_pred + ((size_t)b*NP + n)*4);
    const float parea = (bp.z - bp.x) * (bp.w - bp.y);
    const float* crow = cls_pred + ((size_t)b*NP + n)*NC;
    float mx = -INFINITY;
    for (int k = 0; k < NC; ++k) mx = fmaxf(mx, crow[k]);
    float s = 0.f;
    for (int k = 0; k < NC; ++k) s += expf(crow[k] - mx);
    float* outp = Ct + (size_t)b*NT*NP + n;
    for (int m = 0; m < NT; ++m) {
        const float l1 = fabsf(bp.x - gx0[m]) + fabsf(bp.y - gy0[m]) +
                         fabsf(bp.z - gx1[m]) + fabsf(bp.w - gy1[m]);
        const float xm = fmaxf(bp.x, gx0[m]);
        const float ym = fmaxf(bp.y, gy0[m]);
        const float xM = fminf(bp.z, gx1[m]);
        const float yM = fminf(bp.w, gy1[m]);
        const float inter = fmaxf(xM - xm, 0.f) * fmaxf(yM - ym, 0.f);
        const float iou = inter / (parea + garea[m] - inter + 1e-6f);
        const float pc  = expf(crow[gcls[m]] - mx) / s;
        outp[(size_t)m*NP] = 5.0f*l1 - 2.0f*iou - pc;
    }
}

// ---------------------------------------------------------------------------
// JV shortest-augmenting-path solver. One 64-lane wave per batch, fully
// wave-synchronous. Each lane owns columns j-1 = lane + 64*r, r in [0,15).
// minv/v/used live in registers; only u, p, way in LDS. Faithful fp64 port.
// ---------------------------------------------------------------------------
__global__ __launch_bounds__(64) void jv_kernel(
    const float* __restrict__ Ct,   // [B,M,N]
    int* __restrict__ out)          // preds [B,M] then tgts [B,M] (int32)
{
    const int b    = blockIdx.x;
    const int lane = threadIdx.x;

    __shared__ double u_[NT + 1];
    __shared__ int    p[NP + 1];
    __shared__ int    way[NP + 1];

    double v[SLOTS], minv[SLOTS];
    // lane owns slot r iff lane + 64*r <= 899  ->  r<14 all lanes, r=14 lanes 0..3
    const unsigned ownMask = (lane < 4) ? 0x7FFFu : 0x3FFFu;

    #pragma unroll
    for (int r = 0; r < SLOTS; ++r) v[r] = 0.0;
    for (int j = lane; j <= NP; j += 64) p[j] = 0;
    for (int t = lane; t <= NT; t += 64) u_[t] = 0.0;
    __syncthreads();

    const float* Cb = Ct + (size_t)b*NT*NP;

    for (int i = 1; i <= NT; ++i) {
        unsigned usedMask = 0;
        #pragma unroll
        for (int r = 0; r < SLOTS; ++r) minv[r] = INFINITY;

        int    j0  = 0;
        int    i0  = i;        // p[0] = i
        double ui0 = u_[i];    // = 0 for a fresh row, but read to be faithful

        while (true) {
            // mark column j0 used (j0==0 carries no column bit)
            if (j0 > 0 && ((j0 - 1) & 63) == lane)
                usedMask |= 1u << ((j0 - 1) >> 6);

            const float* crow = Cb + (size_t)(i0 - 1) * NP;

            // scan owned unused columns; update minv/way; local argmin
            double best  = INFINITY;
            int    bestj = 0x7fffffff;
            #pragma unroll
            for (int r = 0; r < SLOTS; ++r) {
                const unsigned bit = 1u << r;
                if ((ownMask & bit) && !(usedMask & bit)) {
                    const int jm1 = lane + (r << 6);
                    const double cur = ((double)crow[jm1] - ui0) - v[r];
                    if (cur < minv[r]) { minv[r] = cur; way[jm1 + 1] = j0; }
                    const double mv = minv[r];
                    if (mv < best) { best = mv; bestj = jm1 + 1; }
                }
            }
            // 64-lane butterfly min-reduce, tie-break = smallest column index
            #pragma unroll
            for (int off = 32; off >= 1; off >>= 1) {
                const double ov = __shfl_xor(best, off, 64);
                const int    oj = __shfl_xor(bestj, off, 64);
                if (ov < best || (ov == best && oj < bestj)) { best = ov; bestj = oj; }
            }
            const double delta = best;
            const int    j1    = bestj;

            // dual updates
            if (lane == 0) u_[i] += delta;   // used column 0 maps to row i
            #pragma unroll
            for (int r = 0; r < SLOTS; ++r) {
                const unsigned bit = 1u << r;
                if (ownMask & bit) {
                    if (usedMask & bit) {
                        const int j = 1 + lane + (r << 6);
                        u_[p[j]] += delta;   // distinct rows per used column
                        v[r] -= delta;
                    } else {
                        minv[r] -= delta;
                    }
                }
            }
            __syncthreads();   // single-wave: compiles to ordering only

            j0 = j1;
            i0 = p[j0];
            if (i0 == 0) break;
            ui0 = u_[i0];
            __syncthreads();
        }

        // augment along alternating path (serial, short)
        __syncthreads();
        if (lane == 0) {
            int jj = j0;
            while (jj != 0) {
                const int jn = way[jj];
                p[jj] = (jn == 0) ? i : p[jn];
                jj = jn;
            }
        }
        __syncthreads();
    }

    // emit matches sorted by pred index (ascending j)
    if (lane == 0) {
        int cnt = 0;
        for (int j = 1; j <= NP; ++j) {
            if (p[j] != 0) {
                out[b*NT + cnt]         = j - 1;      // pred index
                out[NB*NT + b*NT + cnt] = p[j] - 1;   // target index
                ++cnt;
            }
        }
    }
}

extern "C" void kernel_launch(void* const* d_in, const int* in_sizes, int n_in,
                              void* d_out, int out_size, void* d_ws, size_t ws_size,
                              hipStream_t stream)
{
    const float* cls_pred = (const float*)d_in[0];
    const float* bb_pred  = (const float*)d_in[1];
    const int*   cls_gt   = (const int*)d_in[2];
    const float* bb_gt    = (const float*)d_in[3];

    float* Ct = (float*)d_ws;                                // B*M*N floats = 5.76 MB
    const size_t ctBytes = (size_t)NB*NT*NP*sizeof(float);
    const size_t need    = ctBytes + (size_t)NB*NP*sizeof(float2);

    if (ws_size >= need) {
        float2* stats = (float2*)((char*)d_ws + ctBytes);
        softmax_stats_kernel<<<(NB*NP + 3)/4, 256, 0, stream>>>(cls_pred, stats);
        cost_entry_kernel<<<(NB*NT*NP + 255)/256, 256, 0, stream>>>(
            cls_pred, bb_pred, cls_gt, bb_gt, stats, Ct);
    } else {
        dim3 gcost((NP + 255)/256, NB);
        cost_fused_kernel<<<gcost, 256, 0, stream>>>(cls_pred, bb_pred, cls_gt, bb_gt, Ct);
    }
    jv_kernel<<<NB, 64, 0, stream>>>(Ct, (int*)d_out);
}

// Round 3
// 251.605 us; speedup vs baseline: 2.6129x; 2.6129x over previous
//
#include <hip/hip_runtime.h>
#include <math.h>

#define NB 16   // batches
#define NP 900  // predictions (solver columns)
#define NC 91   // classes
#define NT 100  // targets (solver rows)
#define SLOTS 15  // ceil(NP/64) columns owned per lane

// ---------------------------------------------------------------------------
// Kernel A: per-(b,n) softmax stats (max, sum). One 64-lane wave per row.
// ---------------------------------------------------------------------------
__global__ __launch_bounds__(256) void softmax_stats_kernel(
    const float* __restrict__ cls_pred,   // [B*N, K]
    float2* __restrict__ stats)           // [B*N] (max, sum)
{
    const int wave = (blockIdx.x * 256 + threadIdx.x) >> 6;
    const int lane = threadIdx.x & 63;
    if (wave >= NB * NP) return;
    const float* crow = cls_pred + (size_t)wave * NC;

    const float x0 = crow[lane];                                  // lane < 91 always
    const float x1 = (lane + 64 < NC) ? crow[lane + 64] : -INFINITY;
    float mx = fmaxf(x0, x1);
    #pragma unroll
    for (int off = 32; off >= 1; off >>= 1)
        mx = fmaxf(mx, __shfl_xor(mx, off, 64));

    float s = expf(x0 - mx);
    if (lane + 64 < NC) s += expf(x1 - mx);
    #pragma unroll
    for (int off = 32; off >= 1; off >>= 1)
        s += __shfl_xor(s, off, 64);

    if (lane == 0) stats[wave] = make_float2(mx, s);
}

// ---------------------------------------------------------------------------
// Kernel B: one thread per cost entry. Ct[b][m][n] = 5*l1 - 2*iou - prob.
// ---------------------------------------------------------------------------
__global__ __launch_bounds__(256) void cost_entry_kernel(
    const float* __restrict__ cls_pred,   // [B,N,K]
    const float* __restrict__ bb_pred,    // [B,N,4]
    const int*   __restrict__ cls_gt,     // [B,M]
    const float* __restrict__ bb_gt,      // [B,M,4]
    const float2* __restrict__ stats,     // [B*N]
    float* __restrict__ Ct)               // [B,M,N]
{
    const int idx = blockIdx.x * 256 + threadIdx.x;
    if (idx >= NB * NT * NP) return;
    const int n  = idx % NP;
    const int bm = idx / NP;
    const int m  = bm % NT;
    const int b  = bm / NT;

    const float4 bp = *reinterpret_cast<const float4*>(bb_pred + ((size_t)b*NP + n)*4);
    const float4 gt = *reinterpret_cast<const float4*>(bb_gt  + ((size_t)b*NT + m)*4);

    const float l1 = fabsf(bp.x - gt.x) + fabsf(bp.y - gt.y) +
                     fabsf(bp.z - gt.z) + fabsf(bp.w - gt.w);

    const float parea = (bp.z - bp.x) * (bp.w - bp.y);
    const float garea = (gt.z - gt.x) * (gt.w - gt.y);
    const float xm = fmaxf(bp.x, gt.x);
    const float ym = fmaxf(bp.y, gt.y);
    const float xM = fminf(bp.z, gt.z);
    const float yM = fminf(bp.w, gt.w);
    const float inter = fmaxf(xM - xm, 0.f) * fmaxf(yM - ym, 0.f);
    const float iou = inter / (parea + garea - inter + 1e-6f);

    const int c = cls_gt[b*NT + m];
    const float2 st = stats[b*NP + n];
    const float pc = expf(cls_pred[((size_t)(b*NP + n))*NC + c] - st.x) / st.y;

    Ct[idx] = 5.0f*l1 - 2.0f*iou - pc;
}

// ---------------------------------------------------------------------------
// Fallback fused cost kernel (used only if ws_size is too small for stats).
// ---------------------------------------------------------------------------
__global__ __launch_bounds__(256) void cost_fused_kernel(
    const float* __restrict__ cls_pred, const float* __restrict__ bb_pred,
    const int* __restrict__ cls_gt, const float* __restrict__ bb_gt,
    float* __restrict__ Ct)
{
    const int b = blockIdx.y;
    const int n = blockIdx.x * 256 + threadIdx.x;
    __shared__ float gx0[NT], gy0[NT], gx1[NT], gy1[NT], garea[NT];
    __shared__ int   gcls[NT];
    for (int m = threadIdx.x; m < NT; m += 256) {
        const float x0 = bb_gt[((size_t)b*NT + m)*4 + 0];
        const float y0 = bb_gt[((size_t)b*NT + m)*4 + 1];
        const float x1 = bb_gt[((size_t)b*NT + m)*4 + 2];
        const float y1 = bb_gt[((size_t)b*NT + m)*4 + 3];
        gx0[m] = x0; gy0[m] = y0; gx1[m] = x1; gy1[m] = y1;
        garea[m] = (x1 - x0) * (y1 - y0);
        gcls[m]  = cls_gt[b*NT + m];
    }
    __syncthreads();
    if (n >= NP) return;
    const float4 bp = *reinterpret_cast<const float4*>(bb_pred + ((size_t)b*NP + n)*4);
    const float parea = (bp.z - bp.x) * (bp.w - bp.y);
    const float* crow = cls_pred + ((size_t)b*NP + n)*NC;
    float mx = -INFINITY;
    for (int k = 0; k < NC; ++k) mx = fmaxf(mx, crow[k]);
    float s = 0.f;
    for (int k = 0; k < NC; ++k) s += expf(crow[k] - mx);
    float* outp = Ct + (size_t)b*NT*NP + n;
    for (int m = 0; m < NT; ++m) {
        const float l1 = fabsf(bp.x - gx0[m]) + fabsf(bp.y - gy0[m]) +
                         fabsf(bp.z - gx1[m]) + fabsf(bp.w - gy1[m]);
        const float xm = fmaxf(bp.x, gx0[m]);
        const float ym = fmaxf(bp.y, gy0[m]);
        const float xM = fminf(bp.z, gx1[m]);
        const float yM = fminf(bp.w, gy1[m]);
        const float inter = fmaxf(xM - xm, 0.f) * fmaxf(yM - ym, 0.f);
        const float iou = inter / (parea + garea[m] - inter + 1e-6f);
        const float pc  = expf(crow[gcls[m]] - mx) / s;
        outp[(size_t)m*NP] = 5.0f*l1 - 2.0f*iou - pc;
    }
}

// ---------------------------------------------------------------------------
// JV solver: one 64-lane wave per batch, ALL state in registers (no LDS).
// Lazy duals: v/u updated only at phase end (scan reads are phase-start
// values by construction). Exact fp64 shortest-augmenting-path -> same
// unique optimum as the reference.
// ---------------------------------------------------------------------------
__global__ __launch_bounds__(64) void jv_kernel(
    const float* __restrict__ Ct,   // [B,M,N]
    int* __restrict__ out)          // preds [B,M] then tgts [B,M] (int32)
{
    const int b    = blockIdx.x;
    const int lane = threadIdx.x;
    const float* Cb = Ct + (size_t)b*NT*NP;

    double v[SLOTS], minv[SLOTS];
    float  cw[SLOTS], cpre[SLOTS], cnext[SLOTS];
    int    way[SLOTS], p[SLOTS];
    double u0 = 0.0, u1 = 0.0;    // u[lane+1], u[lane+65]

    #pragma unroll
    for (int r = 0; r < SLOTS; ++r) { v[r] = 0.0; p[r] = 0; way[r] = 0; }

    // prefetch row 1 (branchless, clamped)
    #pragma unroll
    for (int r = 0; r < SLOTS; ++r) {
        int ja = 64*r + lane; if (ja > NP-1) ja = NP-1;
        cpre[r] = Cb[ja];
    }

    for (int i = 1; i <= NT; ++i) {
        unsigned usedMask = 0;
        bool it0 = false, it1 = false;   // row-in-tree flags for u slots
        double Dtot = 0.0;
        #pragma unroll
        for (int r = 0; r < SLOTS; ++r) { minv[r] = INFINITY; cw[r] = cpre[r]; }

        // row i enters the tree at phase start (entry delta = 0)
        if (i <= 64) { if (lane == i-1)  it0 = true; }
        else         { if (lane == i-65) it1 = true; }
        double ui0 = (i <= 64) ? __shfl(u0, i-1, 64) : __shfl(u1, i-65, 64);

        // prefetch next phase's first row while this phase runs
        {
            const int ip = (i < NT) ? i + 1 : NT;
            const float* cr = Cb + (size_t)(ip-1)*NP;
            #pragma unroll
            for (int r = 0; r < SLOTS; ++r) {
                int ja = 64*r + lane; if (ja > NP-1) ja = NP-1;
                cnext[r] = cr[ja];
            }
        }

        int j0 = 0;
        int jfinal;
        while (true) {
            // scan owned columns (branchless); local argmin carries j and p[j]
            double best = INFINITY;
            int    pk   = 0x7FFFFFFF;       // (j) | (p[j] << 16)
            #pragma unroll
            for (int r = 0; r < SLOTS; ++r) {
                const int jm1 = 64*r + lane;
                const bool valid = ((r < SLOTS-1) || (lane < 4)) && !((usedMask >> r) & 1u);
                const double cur = valid ? (((double)cw[r] - ui0) - v[r]) : INFINITY;
                if (cur < minv[r]) { minv[r] = cur; way[r] = j0; }
                if (minv[r] < best) { best = minv[r]; pk = (jm1 + 1) | (p[r] << 16); }
            }
            // 64-lane butterfly min-reduce; tie-break = smallest column index
            #pragma unroll
            for (int off = 32; off >= 1; off >>= 1) {
                const double ov  = __shfl_xor(best, off, 64);
                const int    opk = __shfl_xor(pk,   off, 64);
                if (ov < best || (ov == best && (opk & 0xFFFF) < (pk & 0xFFFF))) {
                    best = ov; pk = opk;
                }
            }
            const double delta = best;
            const int    j1    = pk & 0xFFFF;
            const int    pnext = pk >> 16;
            Dtot += delta;
            #pragma unroll
            for (int r = 0; r < SLOTS; ++r) minv[r] -= delta;   // INF stays INF

            // mark column j1 used; record its entry delta (v[r] += Dtot now,
            // -= Dtot_final at phase end  =>  net -= sum of deltas it saw)
            #pragma unroll
            for (int r = 0; r < SLOTS; ++r) {
                if (64*r + lane + 1 == j1) {
                    usedMask |= (1u << r);
                    minv[r] = INFINITY;
                    v[r] += Dtot;
                }
            }

            if (pnext == 0) { jfinal = j1; break; }

            // row pnext enters tree: read its phase-start u BEFORE adjusting
            ui0 = (pnext <= 64) ? __shfl(u0, pnext-1, 64) : __shfl(u1, pnext-65, 64);
            if (pnext <= 64) { if (lane == pnext-1)  { u0 -= Dtot; it0 = true; } }
            else             { if (lane == pnext-65) { u1 -= Dtot; it1 = true; } }

            // load row pnext (branchless, parallel)
            {
                const float* cr = Cb + (size_t)(pnext-1)*NP;
                #pragma unroll
                for (int r = 0; r < SLOTS; ++r) {
                    int ja = 64*r + lane; if (ja > NP-1) ja = NP-1;
                    cw[r] = cr[ja];
                }
            }
            j0 = j1;
        }

        // augment: walk the way[] chain (wave-uniform, register selects + shfl)
        {
            int jc = jfinal;
            while (jc != 0) {
                int wsel = 0;
                #pragma unroll
                for (int r = 0; r < SLOTS; ++r)
                    if (64*r + lane + 1 == jc) wsel = way[r];
                const int jprev = __shfl(wsel, (jc-1) & 63, 64);
                int newrow;
                if (jprev == 0) newrow = i;
                else {
                    int psel = 0;
                    #pragma unroll
                    for (int r = 0; r < SLOTS; ++r)
                        if (64*r + lane + 1 == jprev) psel = p[r];
                    newrow = __shfl(psel, (jprev-1) & 63, 64);
                }
                #pragma unroll
                for (int r = 0; r < SLOTS; ++r)
                    if (64*r + lane + 1 == jc) p[r] = newrow;
                jc = jprev;
            }
        }

        // phase-end dual writeback
        #pragma unroll
        for (int r = 0; r < SLOTS; ++r)
            if ((usedMask >> r) & 1u) v[r] -= Dtot;
        if (it0) u0 += Dtot;
        if (it1) u1 += Dtot;

        #pragma unroll
        for (int r = 0; r < SLOTS; ++r) cpre[r] = cnext[r];
    }

    // emit matches sorted by pred index: rank = #assigned columns with j' < j
    int base = 0;
    #pragma unroll
    for (int r = 0; r < SLOTS; ++r) {
        const unsigned long long mask = __ballot(p[r] != 0);
        if (p[r] != 0) {
            const int rank = base + (int)__popcll(mask & ((1ull << lane) - 1ull));
            out[b*NT + rank]         = 64*r + lane;   // pred index
            out[NB*NT + b*NT + rank] = p[r] - 1;      // target index
        }
        base += (int)__popcll(mask);
    }
}

extern "C" void kernel_launch(void* const* d_in, const int* in_sizes, int n_in,
                              void* d_out, int out_size, void* d_ws, size_t ws_size,
                              hipStream_t stream)
{
    const float* cls_pred = (const float*)d_in[0];
    const float* bb_pred  = (const float*)d_in[1];
    const int*   cls_gt   = (const int*)d_in[2];
    const float* bb_gt    = (const float*)d_in[3];

    float* Ct = (float*)d_ws;                                // B*M*N floats = 5.76 MB
    const size_t ctBytes = (size_t)NB*NT*NP*sizeof(float);
    const size_t need    = ctBytes + (size_t)NB*NP*sizeof(float2);

    if (ws_size >= need) {
        float2* stats = (float2*)((char*)d_ws + ctBytes);
        softmax_stats_kernel<<<(NB*NP + 3)/4, 256, 0, stream>>>(cls_pred, stats);
        cost_entry_kernel<<<(NB*NT*NP + 255)/256, 256, 0, stream>>>(
            cls_pred, bb_pred, cls_gt, bb_gt, stats, Ct);
    } else {
        dim3 gcost((NP + 255)/256, NB);
        cost_fused_kernel<<<gcost, 256, 0, stream>>>(cls_pred, bb_pred, cls_gt, bb_gt, Ct);
    }
    jv_kernel<<<NB, 64, 0, stream>>>(Ct, (int*)d_out);
}

// Round 4
// 57.325 us; speedup vs baseline: 11.4683x; 4.3891x over previous
//
#include <hip/hip_runtime.h>
#include <math.h>

#define NB 16   // batches
#define NP 900  // predictions (solver columns)
#define NC 91   // classes
#define NT 100  // targets (solver rows)
#define SLOTS 15  // ceil(NP/64) columns owned per lane

// ---------------------------------------------------------------------------
// Kernel A: per-(b,n) softmax stats (max, sum). One 64-lane wave per row.
// ---------------------------------------------------------------------------
__global__ __launch_bounds__(256) void softmax_stats_kernel(
    const float* __restrict__ cls_pred,   // [B*N, K]
    float2* __restrict__ stats)           // [B*N] (max, sum)
{
    const int wave = (blockIdx.x * 256 + threadIdx.x) >> 6;
    const int lane = threadIdx.x & 63;
    if (wave >= NB * NP) return;
    const float* crow = cls_pred + (size_t)wave * NC;

    const float x0 = crow[lane];                                  // lane < 91 always
    const float x1 = (lane + 64 < NC) ? crow[lane + 64] : -INFINITY;
    float mx = fmaxf(x0, x1);
    #pragma unroll
    for (int off = 32; off >= 1; off >>= 1)
        mx = fmaxf(mx, __shfl_xor(mx, off, 64));

    float s = expf(x0 - mx);
    if (lane + 64 < NC) s += expf(x1 - mx);
    #pragma unroll
    for (int off = 32; off >= 1; off >>= 1)
        s += __shfl_xor(s, off, 64);

    if (lane == 0) stats[wave] = make_float2(mx, s);
}

// ---------------------------------------------------------------------------
// Kernel B: one thread per cost entry. Ct[b][m][n] = 5*l1 - 2*iou - prob.
// ---------------------------------------------------------------------------
__global__ __launch_bounds__(256) void cost_entry_kernel(
    const float* __restrict__ cls_pred,   // [B,N,K]
    const float* __restrict__ bb_pred,    // [B,N,4]
    const int*   __restrict__ cls_gt,     // [B,M]
    const float* __restrict__ bb_gt,      // [B,M,4]
    const float2* __restrict__ stats,     // [B*N]
    float* __restrict__ Ct)               // [B,M,N]
{
    const int idx = blockIdx.x * 256 + threadIdx.x;
    if (idx >= NB * NT * NP) return;
    const int n  = idx % NP;
    const int bm = idx / NP;
    const int m  = bm % NT;
    const int b  = bm / NT;

    const float4 bp = *reinterpret_cast<const float4*>(bb_pred + ((size_t)b*NP + n)*4);
    const float4 gt = *reinterpret_cast<const float4*>(bb_gt  + ((size_t)b*NT + m)*4);

    const float l1 = fabsf(bp.x - gt.x) + fabsf(bp.y - gt.y) +
                     fabsf(bp.z - gt.z) + fabsf(bp.w - gt.w);

    const float parea = (bp.z - bp.x) * (bp.w - bp.y);
    const float garea = (gt.z - gt.x) * (gt.w - gt.y);
    const float xm = fmaxf(bp.x, gt.x);
    const float ym = fmaxf(bp.y, gt.y);
    const float xM = fminf(bp.z, gt.z);
    const float yM = fminf(bp.w, gt.w);
    const float inter = fmaxf(xM - xm, 0.f) * fmaxf(yM - ym, 0.f);
    const float iou = inter / (parea + garea - inter + 1e-6f);

    const int c = cls_gt[b*NT + m];
    const float2 st = stats[b*NP + n];
    const float pc = expf(cls_pred[((size_t)(b*NP + n))*NC + c] - st.x) / st.y;

    Ct[idx] = 5.0f*l1 - 2.0f*iou - pc;
}

// ---------------------------------------------------------------------------
// Fallback fused cost kernel (used only if ws_size is too small for stats).
// ---------------------------------------------------------------------------
__global__ __launch_bounds__(256) void cost_fused_kernel(
    const float* __restrict__ cls_pred, const float* __restrict__ bb_pred,
    const int* __restrict__ cls_gt, const float* __restrict__ bb_gt,
    float* __restrict__ Ct)
{
    const int b = blockIdx.y;
    const int n = blockIdx.x * 256 + threadIdx.x;
    __shared__ float gx0[NT], gy0[NT], gx1[NT], gy1[NT], garea[NT];
    __shared__ int   gcls[NT];
    for (int m = threadIdx.x; m < NT; m += 256) {
        const float x0 = bb_gt[((size_t)b*NT + m)*4 + 0];
        const float y0 = bb_gt[((size_t)b*NT + m)*4 + 1];
        const float x1 = bb_gt[((size_t)b*NT + m)*4 + 2];
        const float y1 = bb_gt[((size_t)b*NT + m)*4 + 3];
        gx0[m] = x0; gy0[m] = y0; gx1[m] = x1; gy1[m] = y1;
        garea[m] = (x1 - x0) * (y1 - y0);
        gcls[m]  = cls_gt[b*NT + m];
    }
    __syncthreads();
    if (n >= NP) return;
    const float4 bp = *reinterpret_cast<const float4*>(bb_pred + ((size_t)b*NP + n)*4);
    const float parea = (bp.z - bp.x) * (bp.w - bp.y);
    const float* crow = cls_pred + ((size_t)b*NP + n)*NC;
    float mx = -INFINITY;
    for (int k = 0; k < NC; ++k) mx = fmaxf(mx, crow[k]);
    float s = 0.f;
    for (int k = 0; k < NC; ++k) s += expf(crow[k] - mx);
    float* outp = Ct + (size_t)b*NT*NP + n;
    for (int m = 0; m < NT; ++m) {
        const float l1 = fabsf(bp.x - gx0[m]) + fabsf(bp.y - gy0[m]) +
                         fabsf(bp.z - gx1[m]) + fabsf(bp.w - gy1[m]);
        const float xm = fmaxf(bp.x, gx0[m]);
        const float ym = fmaxf(bp.y, gy0[m]);
        const float xM = fminf(bp.z, gx1[m]);
        const float yM = fminf(bp.w, gy1[m]);
        const float inter = fmaxf(xM - xm, 0.f) * fmaxf(yM - ym, 0.f);
        const float iou = inter / (parea + garea[m] - inter + 1e-6f);
        const float pc  = expf(crow[gcls[m]] - mx) / s;
        outp[(size_t)m*NP] = 5.0f*l1 - 2.0f*iou - pc;
    }
}

// ---------------------------------------------------------------------------
// Kernel C: per-row min + argmin of Ct, and greedy column claim.
// One 64-lane wave per (b,m) row. colOwner pre-set to 0xFFFFFFFF.
// u[i] = min_j c[i][j], v = 0: feasible duals with reduced cost 0 at argmin.
// ---------------------------------------------------------------------------
__global__ __launch_bounds__(64) void rowmin_claim_kernel(
    const float* __restrict__ Ct,        // [B*M, N]
    float* __restrict__ u_init,          // [B*M]
    int*   __restrict__ amin,            // [B*M]
    unsigned* __restrict__ colOwner)     // [B, N]
{
    const int row  = blockIdx.x;          // 0 .. NB*NT-1
    const int lane = threadIdx.x;
    const float* cr = Ct + (size_t)row * NP;

    float best = INFINITY; int bj = 0;
    #pragma unroll
    for (int r = 0; r < SLOTS; ++r) {
        const int j = 64*r + lane;
        if ((r < SLOTS-1) || (lane < 4)) {
            const float x = cr[j];
            if (x < best) { best = x; bj = j; }    // ascending j: strict < keeps smallest
        }
    }
    float vmin = best;
    #pragma unroll
    for (int off = 32; off >= 1; off >>= 1)
        vmin = fminf(vmin, __shfl_xor(vmin, off, 64));
    const unsigned long long win = __ballot(best == vmin);
    const int wl = __builtin_ctzll(win);
    const int bjAll = __shfl(bj, wl, 64);
    if (lane == 0) {
        u_init[row] = vmin;
        amin[row]   = bjAll;
        const int b = row / NT, m = row % NT;
        atomicMin(&colOwner[(size_t)b*NP + bjAll], (unsigned)m);
    }
}

// ---------------------------------------------------------------------------
// JV solver: one 64-lane wave per batch, all state in registers. Starts from
// greedy row-reduction assignment; runs shortest-augmenting-path phases only
// for unassigned (collision-loser) rows. Lazy fp64 duals -> exact optimum.
// ---------------------------------------------------------------------------
__device__ __forceinline__ int pop_row(unsigned long long& fm0, unsigned long long& fm1)
{
    if (fm0) { const int l = __builtin_ctzll(fm0); fm0 &= fm0 - 1; return l + 1;  }
    if (fm1) { const int l = __builtin_ctzll(fm1); fm1 &= fm1 - 1; return l + 65; }
    return 0;
}

__global__ __launch_bounds__(64) void jv_kernel(
    const float* __restrict__ Ct,        // [B,M,N]
    const float* __restrict__ u_init,    // [B*M]
    const int*   __restrict__ amin,      // [B*M]
    const unsigned* __restrict__ colOwner, // [B,N]
    int* __restrict__ out)               // preds [B,M] then tgts [B,M] (int32)
{
    const int b    = blockIdx.x;
    const int lane = threadIdx.x;
    const float* Cb = Ct + (size_t)b*NT*NP;

    double v[SLOTS], minv[SLOTS];
    float  cw[SLOTS], cnext[SLOTS];
    int    way[SLOTS], p[SLOTS];

    // duals from row reduction: u0 = u[lane+1], u1 = u[lane+65] (1-based rows)
    double u0 = (double)u_init[b*NT + lane];
    double u1 = (lane < NT-64) ? (double)u_init[b*NT + 64 + lane] : 0.0;

    // greedy assignment from column claims
    #pragma unroll
    for (int r = 0; r < SLOTS; ++r) {
        v[r] = 0.0; way[r] = 0;
        unsigned o = 0xFFFFFFFFu;
        if ((r < SLOTS-1) || (lane < 4)) o = colOwner[(size_t)b*NP + 64*r + lane];
        p[r] = (o == 0xFFFFFFFFu) ? 0 : (int)o + 1;
    }

    // free-row masks (bit l of fm0 = row l+1 free; bit l of fm1 = row l+65)
    const int a0 = amin[b*NT + lane];
    const bool as0 = (colOwner[(size_t)b*NP + a0] == (unsigned)lane);
    bool as1 = true;
    if (lane < NT-64) {
        const int a1 = amin[b*NT + 64 + lane];
        as1 = (colOwner[(size_t)b*NP + a1] == (unsigned)(64 + lane));
    }
    unsigned long long fm0 = __ballot(!as0);
    unsigned long long fm1 = __ballot(!as1 && (lane < NT-64));

    int iCur = pop_row(fm0, fm1);
    if (iCur) {   // prefetch first free row
        const float* cr = Cb + (size_t)(iCur-1)*NP;
        #pragma unroll
        for (int r = 0; r < SLOTS; ++r) {
            int ja = 64*r + lane; if (ja > NP-1) ja = NP-1;
            cnext[r] = cr[ja];
        }
    }

    while (iCur) {
        const int iNext = pop_row(fm0, fm1);

        unsigned usedMask = 0;
        bool it0 = false, it1 = false;
        double Dtot = 0.0;
        #pragma unroll
        for (int r = 0; r < SLOTS; ++r) { minv[r] = INFINITY; cw[r] = cnext[r]; }

        const int i = iCur;
        if (i <= 64) { if (lane == i-1)  it0 = true; }
        else         { if (lane == i-65) it1 = true; }
        double ui0 = (i <= 64) ? __shfl(u0, i-1, 64) : __shfl(u1, i-65, 64);

        if (iNext) {  // prefetch next free row under this phase
            const float* cr = Cb + (size_t)(iNext-1)*NP;
            #pragma unroll
            for (int r = 0; r < SLOTS; ++r) {
                int ja = 64*r + lane; if (ja > NP-1) ja = NP-1;
                cnext[r] = cr[ja];
            }
        }

        int j0 = 0, jfinal;
        while (true) {
            // scan owned columns; update minv/way; local argmin (smallest j)
            double best = INFINITY;
            int    pk   = 0;                      // (p[j] << 10) | j
            #pragma unroll
            for (int r = 0; r < SLOTS; ++r) {
                const int jm1 = 64*r + lane;
                const bool valid = ((r < SLOTS-1) || (lane < 4)) && !((usedMask >> r) & 1u);
                const double cur = valid ? (((double)cw[r] - ui0) - v[r]) : INFINITY;
                if (cur < minv[r]) { minv[r] = cur; way[r] = j0; }
                if (minv[r] < best) { best = minv[r]; pk = (jm1 + 1) | (p[r] << 10); }
            }
            // value-only fp64 min butterfly, then fetch winner's packed key
            double vmin = best;
            #pragma unroll
            for (int off = 32; off >= 1; off >>= 1)
                vmin = fmin(vmin, __shfl_xor(vmin, off, 64));
            const unsigned long long win = __ballot(best == vmin);
            pk = __shfl(pk, __builtin_ctzll(win), 64);

            const double delta = vmin;
            const int    j1    = pk & 1023;
            const int    pnext = pk >> 10;
            Dtot += delta;
            #pragma unroll
            for (int r = 0; r < SLOTS; ++r) minv[r] -= delta;   // INF stays INF

            // mark j1 used; stamp its entry time into v (net -= later deltas)
            #pragma unroll
            for (int r = 0; r < SLOTS; ++r) {
                if (64*r + lane + 1 == j1) {
                    usedMask |= 1u << r;
                    minv[r] = INFINITY;
                    v[r] += Dtot;
                }
            }

            if (pnext == 0) { jfinal = j1; break; }

            // row pnext enters tree: phase-start u read BEFORE entry stamp
            ui0 = (pnext <= 64) ? __shfl(u0, pnext-1, 64) : __shfl(u1, pnext-65, 64);
            if (pnext <= 64) { if (lane == pnext-1)  { u0 -= Dtot; it0 = true; } }
            else             { if (lane == pnext-65) { u1 -= Dtot; it1 = true; } }

            {   // load row pnext (coalesced, branchless)
                const float* cr = Cb + (size_t)(pnext-1)*NP;
                #pragma unroll
                for (int r = 0; r < SLOTS; ++r) {
                    int ja = 64*r + lane; if (ja > NP-1) ja = NP-1;
                    cw[r] = cr[ja];
                }
            }
            j0 = j1;
        }

        // augment along the way[] chain
        {
            int jc = jfinal;
            while (jc != 0) {
                int wsel = 0;
                #pragma unroll
                for (int r = 0; r < SLOTS; ++r)
                    if (64*r + lane + 1 == jc) wsel = way[r];
                const int jprev = __shfl(wsel, (jc-1) & 63, 64);
                int newrow;
                if (jprev == 0) newrow = i;
                else {
                    int psel = 0;
                    #pragma unroll
                    for (int r = 0; r < SLOTS; ++r)
                        if (64*r + lane + 1 == jprev) psel = p[r];
                    newrow = __shfl(psel, (jprev-1) & 63, 64);
                }
                #pragma unroll
                for (int r = 0; r < SLOTS; ++r)
                    if (64*r + lane + 1 == jc) p[r] = newrow;
                jc = jprev;
            }
        }

        // phase-end dual writeback
        #pragma unroll
        for (int r = 0; r < SLOTS; ++r)
            if ((usedMask >> r) & 1u) v[r] -= Dtot;
        if (it0) u0 += Dtot;
        if (it1) u1 += Dtot;

        iCur = iNext;
    }

    // emit matches sorted by pred index: rank = #assigned columns with j' < j
    int base = 0;
    #pragma unroll
    for (int r = 0; r < SLOTS; ++r) {
        const unsigned long long mask = __ballot(p[r] != 0);
        if (p[r] != 0) {
            const int rank = base + (int)__popcll(mask & ((1ull << lane) - 1ull));
            out[b*NT + rank]         = 64*r + lane;   // pred index
            out[NB*NT + b*NT + rank] = p[r] - 1;      // target index
        }
        base += (int)__popcll(mask);
    }
}

extern "C" void kernel_launch(void* const* d_in, const int* in_sizes, int n_in,
                              void* d_out, int out_size, void* d_ws, size_t ws_size,
                              hipStream_t stream)
{
    const float* cls_pred = (const float*)d_in[0];
    const float* bb_pred  = (const float*)d_in[1];
    const int*   cls_gt   = (const int*)d_in[2];
    const float* bb_gt    = (const float*)d_in[3];

    char* base = (char*)d_ws;
    float* Ct = (float*)base;                         // B*M*N floats = 5.76 MB
    const size_t ctBytes    = (size_t)NB*NT*NP*sizeof(float);
    const size_t statsBytes = (size_t)NB*NP*sizeof(float2);     // 115.2 KB
    char* scratch = base + ctBytes;
    // scratch is time-shared: [stats] during cost build, then [colOwner|u|amin]
    unsigned* colOwner = (unsigned*)scratch;                           // 57.6 KB
    float*    u_init   = (float*)(scratch + (size_t)NB*NP*4);         //  6.4 KB
    int*      aminP    = (int*)  (scratch + (size_t)NB*NP*4 + (size_t)NB*NT*4);

    if (ws_size >= ctBytes + statsBytes) {
        float2* stats = (float2*)scratch;
        softmax_stats_kernel<<<(NB*NP + 3)/4, 256, 0, stream>>>(cls_pred, stats);
        cost_entry_kernel<<<(NB*NT*NP + 255)/256, 256, 0, stream>>>(
            cls_pred, bb_pred, cls_gt, bb_gt, stats, Ct);
    } else {
        dim3 gcost((NP + 255)/256, NB);
        cost_fused_kernel<<<gcost, 256, 0, stream>>>(cls_pred, bb_pred, cls_gt, bb_gt, Ct);
    }

    // claim scratch becomes live only after the cost kernels are done (in-order stream)
    hipMemsetAsync(colOwner, 0xFF, (size_t)NB*NP*sizeof(unsigned), stream);
    rowmin_claim_kernel<<<NB*NT, 64, 0, stream>>>(Ct, u_init, aminP, colOwner);
    jv_kernel<<<NB, 64, 0, stream>>>(Ct, u_init, aminP, colOwner, (int*)d_out);
}

// Round 5
// 55.228 us; speedup vs baseline: 11.9037x; 1.0380x over previous
//
#include <hip/hip_runtime.h>
#include <math.h>

#define NB 16   // batches
#define NP 900  // predictions (solver columns)
#define NC 91   // classes
#define NT 100  // targets (solver rows)
#define SLOTS 15  // ceil(NP/64) columns owned per lane

// ---------------------------------------------------------------------------
// Kernel A: per-(b,n) softmax stats (max, sum). One 64-lane wave per row.
// ---------------------------------------------------------------------------
__global__ __launch_bounds__(256) void softmax_stats_kernel(
    const float* __restrict__ cls_pred,   // [B*N, K]
    float2* __restrict__ stats)           // [B*N] (max, sum)
{
    const int wave = (blockIdx.x * 256 + threadIdx.x) >> 6;
    const int lane = threadIdx.x & 63;
    if (wave >= NB * NP) return;
    const float* crow = cls_pred + (size_t)wave * NC;

    const float x0 = crow[lane];                                  // lane < 91 always
    const float x1 = (lane + 64 < NC) ? crow[lane + 64] : -INFINITY;
    float mx = fmaxf(x0, x1);
    #pragma unroll
    for (int off = 32; off >= 1; off >>= 1)
        mx = fmaxf(mx, __shfl_xor(mx, off, 64));

    float s = expf(x0 - mx);
    if (lane + 64 < NC) s += expf(x1 - mx);
    #pragma unroll
    for (int off = 32; off >= 1; off >>= 1)
        s += __shfl_xor(s, off, 64);

    if (lane == 0) stats[wave] = make_float2(mx, s);
}

// ---------------------------------------------------------------------------
// Kernel B: one thread per cost entry. Ct[b][m][n] = 5*l1 - 2*iou - prob.
// Side job: first NB*NP threads init colOwner to 0xFFFFFFFF (replaces the
// pathologically slow in-graph fillBuffer memset).
// ---------------------------------------------------------------------------
__global__ __launch_bounds__(256) void cost_entry_kernel(
    const float* __restrict__ cls_pred,   // [B,N,K]
    const float* __restrict__ bb_pred,    // [B,N,4]
    const int*   __restrict__ cls_gt,     // [B,M]
    const float* __restrict__ bb_gt,      // [B,M,4]
    const float2* __restrict__ stats,     // [B*N]
    float* __restrict__ Ct,               // [B,M,N]
    unsigned* __restrict__ colOwner)      // [B,N] (init side job)
{
    const int idx = blockIdx.x * 256 + threadIdx.x;
    if (idx < NB * NP) colOwner[idx] = 0xFFFFFFFFu;
    if (idx >= NB * NT * NP) return;
    const int n  = idx % NP;
    const int bm = idx / NP;
    const int m  = bm % NT;
    const int b  = bm / NT;

    const float4 bp = *reinterpret_cast<const float4*>(bb_pred + ((size_t)b*NP + n)*4);
    const float4 gt = *reinterpret_cast<const float4*>(bb_gt  + ((size_t)b*NT + m)*4);

    const float l1 = fabsf(bp.x - gt.x) + fabsf(bp.y - gt.y) +
                     fabsf(bp.z - gt.z) + fabsf(bp.w - gt.w);

    const float parea = (bp.z - bp.x) * (bp.w - bp.y);
    const float garea = (gt.z - gt.x) * (gt.w - gt.y);
    const float xm = fmaxf(bp.x, gt.x);
    const float ym = fmaxf(bp.y, gt.y);
    const float xM = fminf(bp.z, gt.z);
    const float yM = fminf(bp.w, gt.w);
    const float inter = fmaxf(xM - xm, 0.f) * fmaxf(yM - ym, 0.f);
    const float iou = inter / (parea + garea - inter + 1e-6f);

    const int c = cls_gt[b*NT + m];
    const float2 st = stats[b*NP + n];
    const float pc = expf(cls_pred[((size_t)(b*NP + n))*NC + c] - st.x) / st.y;

    Ct[idx] = 5.0f*l1 - 2.0f*iou - pc;
}

// ---------------------------------------------------------------------------
// Fallback fused cost kernel (used only if ws_size is too small for stats).
// Also inits colOwner.
// ---------------------------------------------------------------------------
__global__ __launch_bounds__(256) void cost_fused_kernel(
    const float* __restrict__ cls_pred, const float* __restrict__ bb_pred,
    const int* __restrict__ cls_gt, const float* __restrict__ bb_gt,
    float* __restrict__ Ct, unsigned* __restrict__ colOwner)
{
    const int b = blockIdx.y;
    const int n = blockIdx.x * 256 + threadIdx.x;
    __shared__ float gx0[NT], gy0[NT], gx1[NT], gy1[NT], garea[NT];
    __shared__ int   gcls[NT];
    for (int m = threadIdx.x; m < NT; m += 256) {
        const float x0 = bb_gt[((size_t)b*NT + m)*4 + 0];
        const float y0 = bb_gt[((size_t)b*NT + m)*4 + 1];
        const float x1 = bb_gt[((size_t)b*NT + m)*4 + 2];
        const float y1 = bb_gt[((size_t)b*NT + m)*4 + 3];
        gx0[m] = x0; gy0[m] = y0; gx1[m] = x1; gy1[m] = y1;
        garea[m] = (x1 - x0) * (y1 - y0);
        gcls[m]  = cls_gt[b*NT + m];
    }
    __syncthreads();
    if (n >= NP) return;
    colOwner[(size_t)b*NP + n] = 0xFFFFFFFFu;
    const float4 bp = *reinterpret_cast<const float4*>(bb_pred + ((size_t)b*NP + n)*4);
    const float parea = (bp.z - bp.x) * (bp.w - bp.y);
    const float* crow = cls_pred + ((size_t)b*NP + n)*NC;
    float mx = -INFINITY;
    for (int k = 0; k < NC; ++k) mx = fmaxf(mx, crow[k]);
    float s = 0.f;
    for (int k = 0; k < NC; ++k) s += expf(crow[k] - mx);
    float* outp = Ct + (size_t)b*NT*NP + n;
    for (int m = 0; m < NT; ++m) {
        const float l1 = fabsf(bp.x - gx0[m]) + fabsf(bp.y - gy0[m]) +
                         fabsf(bp.z - gx1[m]) + fabsf(bp.w - gy1[m]);
        const float xm = fmaxf(bp.x, gx0[m]);
        const float ym = fmaxf(bp.y, gy0[m]);
        const float xM = fminf(bp.z, gx1[m]);
        const float yM = fminf(bp.w, gy1[m]);
        const float inter = fmaxf(xM - xm, 0.f) * fmaxf(yM - ym, 0.f);
        const float iou = inter / (parea + garea[m] - inter + 1e-6f);
        const float pc  = expf(crow[gcls[m]] - mx) / s;
        outp[(size_t)m*NP] = 5.0f*l1 - 2.0f*iou - pc;
    }
}

// ---------------------------------------------------------------------------
// Kernel C: per-row min + argmin of Ct, and greedy column claim.
// One 64-lane wave per (b,m) row. colOwner pre-set to 0xFFFFFFFF.
// u[i] = min_j c[i][j], v = 0: feasible duals with reduced cost 0 at argmin.
// ---------------------------------------------------------------------------
__global__ __launch_bounds__(64) void rowmin_claim_kernel(
    const float* __restrict__ Ct,        // [B*M, N]
    float* __restrict__ u_init,          // [B*M]
    int*   __restrict__ amin,            // [B*M]
    unsigned* __restrict__ colOwner)     // [B, N]
{
    const int row  = blockIdx.x;          // 0 .. NB*NT-1
    const int lane = threadIdx.x;
    const float* cr = Ct + (size_t)row * NP;

    float best = INFINITY; int bj = 0;
    #pragma unroll
    for (int r = 0; r < SLOTS; ++r) {
        const int j = 64*r + lane;
        if ((r < SLOTS-1) || (lane < 4)) {
            const float x = cr[j];
            if (x < best) { best = x; bj = j; }    // ascending j: strict < keeps smallest
        }
    }
    float vmin = best;
    #pragma unroll
    for (int off = 32; off >= 1; off >>= 1)
        vmin = fminf(vmin, __shfl_xor(vmin, off, 64));
    const unsigned long long win = __ballot(best == vmin);
    const int wl = __builtin_ctzll(win);
    const int bjAll = __shfl(bj, wl, 64);
    if (lane == 0) {
        u_init[row] = vmin;
        amin[row]   = bjAll;
        const int b = row / NT, m = row % NT;
        atomicMin(&colOwner[(size_t)b*NP + bjAll], (unsigned)m);
    }
}

// ---------------------------------------------------------------------------
// JV solver: one 64-lane wave per batch, all state in registers. Starts from
// greedy row-reduction assignment; runs shortest-augmenting-path phases only
// for unassigned (collision-loser) rows. Lazy fp64 duals -> exact optimum.
// ---------------------------------------------------------------------------
__device__ __forceinline__ int pop_row(unsigned long long& fm0, unsigned long long& fm1)
{
    if (fm0) { const int l = __builtin_ctzll(fm0); fm0 &= fm0 - 1; return l + 1;  }
    if (fm1) { const int l = __builtin_ctzll(fm1); fm1 &= fm1 - 1; return l + 65; }
    return 0;
}

__global__ __launch_bounds__(64) void jv_kernel(
    const float* __restrict__ Ct,        // [B,M,N]
    const float* __restrict__ u_init,    // [B*M]
    const int*   __restrict__ amin,      // [B*M]
    const unsigned* __restrict__ colOwner, // [B,N]
    int* __restrict__ out)               // preds [B,M] then tgts [B,M] (int32)
{
    const int b    = blockIdx.x;
    const int lane = threadIdx.x;
    const float* Cb = Ct + (size_t)b*NT*NP;

    double v[SLOTS], minv[SLOTS];
    float  cw[SLOTS], cnext[SLOTS];
    int    way[SLOTS], p[SLOTS];

    // duals from row reduction: u0 = u[lane+1], u1 = u[lane+65] (1-based rows)
    double u0 = (double)u_init[b*NT + lane];
    double u1 = (lane < NT-64) ? (double)u_init[b*NT + 64 + lane] : 0.0;

    // greedy assignment from column claims
    #pragma unroll
    for (int r = 0; r < SLOTS; ++r) {
        v[r] = 0.0; way[r] = 0;
        unsigned o = 0xFFFFFFFFu;
        if ((r < SLOTS-1) || (lane < 4)) o = colOwner[(size_t)b*NP + 64*r + lane];
        p[r] = (o == 0xFFFFFFFFu) ? 0 : (int)o + 1;
    }

    // free-row masks (bit l of fm0 = row l+1 free; bit l of fm1 = row l+65)
    const int a0 = amin[b*NT + lane];
    const bool as0 = (colOwner[(size_t)b*NP + a0] == (unsigned)lane);
    bool as1 = true;
    if (lane < NT-64) {
        const int a1 = amin[b*NT + 64 + lane];
        as1 = (colOwner[(size_t)b*NP + a1] == (unsigned)(64 + lane));
    }
    unsigned long long fm0 = __ballot(!as0);
    unsigned long long fm1 = __ballot(!as1 && (lane < NT-64));

    int iCur = pop_row(fm0, fm1);
    if (iCur) {   // prefetch first free row
        const float* cr = Cb + (size_t)(iCur-1)*NP;
        #pragma unroll
        for (int r = 0; r < SLOTS; ++r) {
            int ja = 64*r + lane; if (ja > NP-1) ja = NP-1;
            cnext[r] = cr[ja];
        }
    }

    while (iCur) {
        const int iNext = pop_row(fm0, fm1);

        unsigned usedMask = 0;
        bool it0 = false, it1 = false;
        double Dtot = 0.0;
        #pragma unroll
        for (int r = 0; r < SLOTS; ++r) { minv[r] = INFINITY; cw[r] = cnext[r]; }

        const int i = iCur;
        if (i <= 64) { if (lane == i-1)  it0 = true; }
        else         { if (lane == i-65) it1 = true; }
        double ui0 = (i <= 64) ? __shfl(u0, i-1, 64) : __shfl(u1, i-65, 64);

        if (iNext) {  // prefetch next free row under this phase
            const float* cr = Cb + (size_t)(iNext-1)*NP;
            #pragma unroll
            for (int r = 0; r < SLOTS; ++r) {
                int ja = 64*r + lane; if (ja > NP-1) ja = NP-1;
                cnext[r] = cr[ja];
            }
        }

        int j0 = 0, jfinal;
        while (true) {
            // scan owned columns; update minv/way; local argmin (smallest j)
            double best = INFINITY;
            int    pk   = 0;                      // (p[j] << 10) | j
            #pragma unroll
            for (int r = 0; r < SLOTS; ++r) {
                const int jm1 = 64*r + lane;
                const bool valid = ((r < SLOTS-1) || (lane < 4)) && !((usedMask >> r) & 1u);
                const double cur = valid ? (((double)cw[r] - ui0) - v[r]) : INFINITY;
                if (cur < minv[r]) { minv[r] = cur; way[r] = j0; }
                if (minv[r] < best) { best = minv[r]; pk = (jm1 + 1) | (p[r] << 10); }
            }
            // value-only fp64 min butterfly, then fetch winner's packed key
            double vmin = best;
            #pragma unroll
            for (int off = 32; off >= 1; off >>= 1)
                vmin = fmin(vmin, __shfl_xor(vmin, off, 64));
            const unsigned long long win = __ballot(best == vmin);
            pk = __shfl(pk, __builtin_ctzll(win), 64);

            const double delta = vmin;
            const int    j1    = pk & 1023;
            const int    pnext = pk >> 10;
            Dtot += delta;
            #pragma unroll
            for (int r = 0; r < SLOTS; ++r) minv[r] -= delta;   // INF stays INF

            // mark j1 used; stamp its entry time into v (net -= later deltas)
            #pragma unroll
            for (int r = 0; r < SLOTS; ++r) {
                if (64*r + lane + 1 == j1) {
                    usedMask |= 1u << r;
                    minv[r] = INFINITY;
                    v[r] += Dtot;
                }
            }

            if (pnext == 0) { jfinal = j1; break; }

            // row pnext enters tree: phase-start u read BEFORE entry stamp
            ui0 = (pnext <= 64) ? __shfl(u0, pnext-1, 64) : __shfl(u1, pnext-65, 64);
            if (pnext <= 64) { if (lane == pnext-1)  { u0 -= Dtot; it0 = true; } }
            else             { if (lane == pnext-65) { u1 -= Dtot; it1 = true; } }

            {   // load row pnext (coalesced, branchless)
                const float* cr = Cb + (size_t)(pnext-1)*NP;
                #pragma unroll
                for (int r = 0; r < SLOTS; ++r) {
                    int ja = 64*r + lane; if (ja > NP-1) ja = NP-1;
                    cw[r] = cr[ja];
                }
            }
            j0 = j1;
        }

        // augment along the way[] chain
        {
            int jc = jfinal;
            while (jc != 0) {
                int wsel = 0;
                #pragma unroll
                for (int r = 0; r < SLOTS; ++r)
                    if (64*r + lane + 1 == jc) wsel = way[r];
                const int jprev = __shfl(wsel, (jc-1) & 63, 64);
                int newrow;
                if (jprev == 0) newrow = i;
                else {
                    int psel = 0;
                    #pragma unroll
                    for (int r = 0; r < SLOTS; ++r)
                        if (64*r + lane + 1 == jprev) psel = p[r];
                    newrow = __shfl(psel, (jprev-1) & 63, 64);
                }
                #pragma unroll
                for (int r = 0; r < SLOTS; ++r)
                    if (64*r + lane + 1 == jc) p[r] = newrow;
                jc = jprev;
            }
        }

        // phase-end dual writeback
        #pragma unroll
        for (int r = 0; r < SLOTS; ++r)
            if ((usedMask >> r) & 1u) v[r] -= Dtot;
        if (it0) u0 += Dtot;
        if (it1) u1 += Dtot;

        iCur = iNext;
    }

    // emit matches sorted by pred index: rank = #assigned columns with j' < j
    int base = 0;
    #pragma unroll
    for (int r = 0; r < SLOTS; ++r) {
        const unsigned long long mask = __ballot(p[r] != 0);
        if (p[r] != 0) {
            const int rank = base + (int)__popcll(mask & ((1ull << lane) - 1ull));
            out[b*NT + rank]         = 64*r + lane;   // pred index
            out[NB*NT + b*NT + rank] = p[r] - 1;      // target index
        }
        base += (int)__popcll(mask);
    }
}

extern "C" void kernel_launch(void* const* d_in, const int* in_sizes, int n_in,
                              void* d_out, int out_size, void* d_ws, size_t ws_size,
                              hipStream_t stream)
{
    const float* cls_pred = (const float*)d_in[0];
    const float* bb_pred  = (const float*)d_in[1];
    const int*   cls_gt   = (const int*)d_in[2];
    const float* bb_gt    = (const float*)d_in[3];

    char* base = (char*)d_ws;
    float* Ct = (float*)base;                         // B*M*N floats = 5.76 MB
    const size_t ctBytes    = (size_t)NB*NT*NP*sizeof(float);
    const size_t statsBytes = (size_t)NB*NP*sizeof(float2);     // 115.2 KB
    // layout: [Ct][stats][colOwner][u_init][amin] — no overlap, no memset needed
    float2*   stats    = (float2*)(base + ctBytes);
    unsigned* colOwner = (unsigned*)(base + ctBytes + statsBytes);
    float*    u_init   = (float*)(base + ctBytes + statsBytes + (size_t)NB*NP*4);
    int*      aminP    = (int*)(base + ctBytes + statsBytes + (size_t)NB*NP*4 + (size_t)NB*NT*4);
    const size_t need = ctBytes + statsBytes + (size_t)NB*NP*4 + (size_t)NB*NT*8;

    if (ws_size >= need) {
        softmax_stats_kernel<<<(NB*NP + 3)/4, 256, 0, stream>>>(cls_pred, stats);
        cost_entry_kernel<<<(NB*NT*NP + 255)/256, 256, 0, stream>>>(
            cls_pred, bb_pred, cls_gt, bb_gt, stats, Ct, colOwner);
    } else {
        // fallback layout without stats buffer
        colOwner = (unsigned*)(base + ctBytes);
        u_init   = (float*)(base + ctBytes + (size_t)NB*NP*4);
        aminP    = (int*)(base + ctBytes + (size_t)NB*NP*4 + (size_t)NB*NT*4);
        dim3 gcost((NP + 255)/256, NB);
        cost_fused_kernel<<<gcost, 256, 0, stream>>>(cls_pred, bb_pred, cls_gt, bb_gt, Ct, colOwner);
    }

    rowmin_claim_kernel<<<NB*NT, 64, 0, stream>>>(Ct, u_init, aminP, colOwner);
    jv_kernel<<<NB, 64, 0, stream>>>(Ct, u_init, aminP, colOwner, (int*)d_out);
}

// Round 6
// 54.994 us; speedup vs baseline: 11.9544x; 1.0043x over previous
//
#include <hip/hip_runtime.h>
#include <math.h>

#define NB 16   // batches
#define NP 900  // predictions (solver columns)
#define NC 91   // classes
#define NT 100  // targets (solver rows)
#define SLOTS 15  // ceil(NP/64) columns owned per lane

// ---------------------------------------------------------------------------
// Kernel A: per-(b,n) softmax stats (max, 1/sum). One 64-lane wave per row.
// Side job: init colOwner to 0xFFFFFFFF (in-order stream orders it before
// the claim atomics in the costrow kernel).
// ---------------------------------------------------------------------------
__global__ __launch_bounds__(256) void softmax_stats_kernel(
    const float* __restrict__ cls_pred,   // [B*N, K]
    float2* __restrict__ stats,           // [B*N] (max, 1/sum)
    unsigned* __restrict__ colOwner)      // [B*N] init side job
{
    const int gtid = blockIdx.x * 256 + threadIdx.x;
    if (gtid < NB * NP) colOwner[gtid] = 0xFFFFFFFFu;

    const int wave = gtid >> 6;
    const int lane = threadIdx.x & 63;
    if (wave >= NB * NP) return;
    const float* crow = cls_pred + (size_t)wave * NC;

    const float x0 = crow[lane];                                  // lane < 91 always
    const float x1 = (lane + 64 < NC) ? crow[lane + 64] : -INFINITY;
    float mx = fmaxf(x0, x1);
    #pragma unroll
    for (int off = 32; off >= 1; off >>= 1)
        mx = fmaxf(mx, __shfl_xor(mx, off, 64));

    float s = expf(x0 - mx);
    if (lane + 64 < NC) s += expf(x1 - mx);
    #pragma unroll
    for (int off = 32; off >= 1; off >>= 1)
        s += __shfl_xor(s, off, 64);

    if (lane == 0) stats[wave] = make_float2(mx, 1.0f / s);
}

// ---------------------------------------------------------------------------
// Kernel B: fused cost + row-min + greedy claim. One 64-lane wave per (b,m)
// row; lane computes 15 entries (n = 64r+lane), writes the Ct row coalesced,
// reduces the row min/argmin in-wave, and lane 0 claims the argmin column.
// u[i] = min_j c[i][j], v = 0: feasible duals, reduced cost 0 at argmin.
// ---------------------------------------------------------------------------
__global__ __launch_bounds__(256) void costrow_kernel(
    const float* __restrict__ cls_pred,   // [B,N,K]
    const float* __restrict__ bb_pred,    // [B,N,4]
    const int*   __restrict__ cls_gt,     // [B,M]
    const float* __restrict__ bb_gt,      // [B,M,4]
    const float2* __restrict__ stats,     // [B*N] (max, 1/sum)
    float* __restrict__ Ct,               // [B*M, N]
    float* __restrict__ u_init,           // [B*M]
    int*   __restrict__ amin,             // [B*M]
    unsigned* __restrict__ colOwner)      // [B, N]
{
    const int row  = (blockIdx.x * 256 + threadIdx.x) >> 6;   // b*NT + m
    const int lane = threadIdx.x & 63;
    if (row >= NB * NT) return;
    const int b = row / NT;

    const float4 gt = *reinterpret_cast<const float4*>(bb_gt + (size_t)row*4);
    const float garea = (gt.z - gt.x) * (gt.w - gt.y);
    const int   c     = cls_gt[row];

    float* outr = Ct + (size_t)row * NP;
    float best = INFINITY; int bj = 0;

    #pragma unroll
    for (int r = 0; r < SLOTS; ++r) {
        const int n = 64*r + lane;
        if ((r < SLOTS-1) || (lane < 4)) {
            const float4 bp = *reinterpret_cast<const float4*>(bb_pred + ((size_t)b*NP + n)*4);
            const float2 st = stats[b*NP + n];
            const float  x  = cls_pred[((size_t)(b*NP + n))*NC + c];

            const float l1 = fabsf(bp.x - gt.x) + fabsf(bp.y - gt.y) +
                             fabsf(bp.z - gt.z) + fabsf(bp.w - gt.w);
            const float parea = (bp.z - bp.x) * (bp.w - bp.y);
            const float xm = fmaxf(bp.x, gt.x);
            const float ym = fmaxf(bp.y, gt.y);
            const float xM = fminf(bp.z, gt.z);
            const float yM = fminf(bp.w, gt.w);
            const float inter = fmaxf(xM - xm, 0.f) * fmaxf(yM - ym, 0.f);
            const float iou = inter / (parea + garea - inter + 1e-6f);
            const float pc  = expf(x - st.x) * st.y;

            const float cost = 5.0f*l1 - 2.0f*iou - pc;
            outr[n] = cost;
            if (cost < best) { best = cost; bj = n; }   // ascending n per lane
        }
    }

    float vmin = best;
    #pragma unroll
    for (int off = 32; off >= 1; off >>= 1)
        vmin = fminf(vmin, __shfl_xor(vmin, off, 64));
    const unsigned long long win = __ballot(best == vmin);
    const int bjAll = __shfl(bj, __builtin_ctzll(win), 64);
    if (lane == 0) {
        u_init[row] = vmin;
        amin[row]   = bjAll;
        atomicMin(&colOwner[(size_t)b*NP + bjAll], (unsigned)(row % NT));
    }
}

// ---------------------------------------------------------------------------
// JV solver: one 64-lane wave per batch, all state in registers. Starts from
// greedy row-reduction assignment; runs shortest-augmenting-path phases only
// for unassigned (collision-loser) rows. Lazy fp64 duals -> exact optimum.
// ---------------------------------------------------------------------------
__device__ __forceinline__ int pop_row(unsigned long long& fm0, unsigned long long& fm1)
{
    if (fm0) { const int l = __builtin_ctzll(fm0); fm0 &= fm0 - 1; return l + 1;  }
    if (fm1) { const int l = __builtin_ctzll(fm1); fm1 &= fm1 - 1; return l + 65; }
    return 0;
}

__global__ __launch_bounds__(64) void jv_kernel(
    const float* __restrict__ Ct,        // [B,M,N]
    const float* __restrict__ u_init,    // [B*M]
    const int*   __restrict__ amin,      // [B*M]
    const unsigned* __restrict__ colOwner, // [B,N]
    int* __restrict__ out)               // preds [B,M] then tgts [B,M] (int32)
{
    const int b    = blockIdx.x;
    const int lane = threadIdx.x;
    const float* Cb = Ct + (size_t)b*NT*NP;

    double v[SLOTS], minv[SLOTS];
    float  cw[SLOTS], cnext[SLOTS];
    int    way[SLOTS], p[SLOTS];

    // duals from row reduction: u0 = u[lane+1], u1 = u[lane+65] (1-based rows)
    double u0 = (double)u_init[b*NT + lane];
    double u1 = (lane < NT-64) ? (double)u_init[b*NT + 64 + lane] : 0.0;

    // greedy assignment from column claims
    #pragma unroll
    for (int r = 0; r < SLOTS; ++r) {
        v[r] = 0.0; way[r] = 0;
        unsigned o = 0xFFFFFFFFu;
        if ((r < SLOTS-1) || (lane < 4)) o = colOwner[(size_t)b*NP + 64*r + lane];
        p[r] = (o == 0xFFFFFFFFu) ? 0 : (int)o + 1;
    }

    // free-row masks (bit l of fm0 = row l+1 free; bit l of fm1 = row l+65)
    const int a0 = amin[b*NT + lane];
    const bool as0 = (colOwner[(size_t)b*NP + a0] == (unsigned)lane);
    bool as1 = true;
    if (lane < NT-64) {
        const int a1 = amin[b*NT + 64 + lane];
        as1 = (colOwner[(size_t)b*NP + a1] == (unsigned)(64 + lane));
    }
    unsigned long long fm0 = __ballot(!as0);
    unsigned long long fm1 = __ballot(!as1 && (lane < NT-64));

    int iCur = pop_row(fm0, fm1);
    if (iCur) {   // prefetch first free row
        const float* cr = Cb + (size_t)(iCur-1)*NP;
        #pragma unroll
        for (int r = 0; r < SLOTS; ++r) {
            int ja = 64*r + lane; if (ja > NP-1) ja = NP-1;
            cnext[r] = cr[ja];
        }
    }

    while (iCur) {
        const int iNext = pop_row(fm0, fm1);

        unsigned usedMask = 0;
        bool it0 = false, it1 = false;
        double Dtot = 0.0;
        #pragma unroll
        for (int r = 0; r < SLOTS; ++r) { minv[r] = INFINITY; cw[r] = cnext[r]; }

        const int i = iCur;
        if (i <= 64) { if (lane == i-1)  it0 = true; }
        else         { if (lane == i-65) it1 = true; }
        double ui0 = (i <= 64) ? __shfl(u0, i-1, 64) : __shfl(u1, i-65, 64);

        if (iNext) {  // prefetch next free row under this phase
            const float* cr = Cb + (size_t)(iNext-1)*NP;
            #pragma unroll
            for (int r = 0; r < SLOTS; ++r) {
                int ja = 64*r + lane; if (ja > NP-1) ja = NP-1;
                cnext[r] = cr[ja];
            }
        }

        int j0 = 0, jfinal;
        while (true) {
            // scan owned columns; update minv/way; local argmin (smallest j)
            double best = INFINITY;
            int    pk   = 0;                      // (p[j] << 10) | j
            #pragma unroll
            for (int r = 0; r < SLOTS; ++r) {
                const int jm1 = 64*r + lane;
                const bool valid = ((r < SLOTS-1) || (lane < 4)) && !((usedMask >> r) & 1u);
                const double cur = valid ? (((double)cw[r] - ui0) - v[r]) : INFINITY;
                if (cur < minv[r]) { minv[r] = cur; way[r] = j0; }
                if (minv[r] < best) { best = minv[r]; pk = (jm1 + 1) | (p[r] << 10); }
            }
            // value-only fp64 min butterfly, then fetch winner's packed key
            double vmin = best;
            #pragma unroll
            for (int off = 32; off >= 1; off >>= 1)
                vmin = fmin(vmin, __shfl_xor(vmin, off, 64));
            const unsigned long long win = __ballot(best == vmin);
            pk = __shfl(pk, __builtin_ctzll(win), 64);

            const double delta = vmin;
            const int    j1    = pk & 1023;
            const int    pnext = pk >> 10;
            Dtot += delta;
            #pragma unroll
            for (int r = 0; r < SLOTS; ++r) minv[r] -= delta;   // INF stays INF

            // mark j1 used; stamp its entry time into v (net -= later deltas)
            #pragma unroll
            for (int r = 0; r < SLOTS; ++r) {
                if (64*r + lane + 1 == j1) {
                    usedMask |= 1u << r;
                    minv[r] = INFINITY;
                    v[r] += Dtot;
                }
            }

            if (pnext == 0) { jfinal = j1; break; }

            // row pnext enters tree: phase-start u read BEFORE entry stamp
            ui0 = (pnext <= 64) ? __shfl(u0, pnext-1, 64) : __shfl(u1, pnext-65, 64);
            if (pnext <= 64) { if (lane == pnext-1)  { u0 -= Dtot; it0 = true; } }
            else             { if (lane == pnext-65) { u1 -= Dtot; it1 = true; } }

            {   // load row pnext (coalesced, branchless)
                const float* cr = Cb + (size_t)(pnext-1)*NP;
                #pragma unroll
                for (int r = 0; r < SLOTS; ++r) {
                    int ja = 64*r + lane; if (ja > NP-1) ja = NP-1;
                    cw[r] = cr[ja];
                }
            }
            j0 = j1;
        }

        // augment along the way[] chain
        {
            int jc = jfinal;
            while (jc != 0) {
                int wsel = 0;
                #pragma unroll
                for (int r = 0; r < SLOTS; ++r)
                    if (64*r + lane + 1 == jc) wsel = way[r];
                const int jprev = __shfl(wsel, (jc-1) & 63, 64);
                int newrow;
                if (jprev == 0) newrow = i;
                else {
                    int psel = 0;
                    #pragma unroll
                    for (int r = 0; r < SLOTS; ++r)
                        if (64*r + lane + 1 == jprev) psel = p[r];
                    newrow = __shfl(psel, (jprev-1) & 63, 64);
                }
                #pragma unroll
                for (int r = 0; r < SLOTS; ++r)
                    if (64*r + lane + 1 == jc) p[r] = newrow;
                jc = jprev;
            }
        }

        // phase-end dual writeback
        #pragma unroll
        for (int r = 0; r < SLOTS; ++r)
            if ((usedMask >> r) & 1u) v[r] -= Dtot;
        if (it0) u0 += Dtot;
        if (it1) u1 += Dtot;

        iCur = iNext;
    }

    // emit matches sorted by pred index: rank = #assigned columns with j' < j
    int base = 0;
    #pragma unroll
    for (int r = 0; r < SLOTS; ++r) {
        const unsigned long long mask = __ballot(p[r] != 0);
        if (p[r] != 0) {
            const int rank = base + (int)__popcll(mask & ((1ull << lane) - 1ull));
            out[b*NT + rank]         = 64*r + lane;   // pred index
            out[NB*NT + b*NT + rank] = p[r] - 1;      // target index
        }
        base += (int)__popcll(mask);
    }
}

extern "C" void kernel_launch(void* const* d_in, const int* in_sizes, int n_in,
                              void* d_out, int out_size, void* d_ws, size_t ws_size,
                              hipStream_t stream)
{
    const float* cls_pred = (const float*)d_in[0];
    const float* bb_pred  = (const float*)d_in[1];
    const int*   cls_gt   = (const int*)d_in[2];
    const float* bb_gt    = (const float*)d_in[3];

    char* base = (char*)d_ws;
    const size_t ctBytes    = (size_t)NB*NT*NP*sizeof(float);   // 5.76 MB
    const size_t statsBytes = (size_t)NB*NP*sizeof(float2);     // 115.2 KB
    // layout: [Ct][stats][colOwner][u_init][amin]
    float*    Ct       = (float*)base;
    float2*   stats    = (float2*)(base + ctBytes);
    unsigned* colOwner = (unsigned*)(base + ctBytes + statsBytes);
    float*    u_init   = (float*)(base + ctBytes + statsBytes + (size_t)NB*NP*4);
    int*      aminP    = (int*)(base + ctBytes + statsBytes + (size_t)NB*NP*4 + (size_t)NB*NT*4);

    // stats: one wave per (b,n); also inits colOwner
    softmax_stats_kernel<<<(NB*NP + 3)/4, 256, 0, stream>>>(cls_pred, stats, colOwner);
    // fused cost + row-min + claim: one wave per (b,m)
    costrow_kernel<<<(NB*NT + 3)/4, 256, 0, stream>>>(
        cls_pred, bb_pred, cls_gt, bb_gt, stats, Ct, u_init, aminP, colOwner);
    // solver: one wave per batch
    jv_kernel<<<NB, 64, 0, stream>>>(Ct, u_init, aminP, colOwner, (int*)d_out);
}